// Round 6
// baseline (416.808 us; speedup 1.0000x reference)
//
#include <hip/hip_runtime.h>
#include <hip/hip_bf16.h>

// FeatureAdaption R6: barrier-free streaming design. No LDS at all; B-operand
// fragments are read per-MFMA straight from L2-resident tile-major weights;
// waves fully independent, deep vmcnt pipelining, high VGPR budget.
// conv1(256->256) -> conv2(256->72)=offsets -> deform conv v1 + ReLU.
// B=8, C=256, H=W=64, dg=4, K=9.

typedef __attribute__((ext_vector_type(8))) short bf16x8;
typedef __attribute__((ext_vector_type(4))) float f32x4;

static __device__ __forceinline__ ushort f2bf(float f) {
  __hip_bfloat16 h = __float2bfloat16(f);
  return *reinterpret_cast<ushort*>(&h);
}
static __device__ __forceinline__ float bf2f(ushort u) {
  union { uint u32; float f; } cv;
  cv.u32 = ((uint)u) << 16;
  return cv.f;
}

// ---------------- weight prep: plain tile-major bf16 ----------------
// Layout: [ti][co][k6]  (k6 = 0..63 channel-in-chunk)
// conv  : ti = kk*4 + chunk, value = w[(co*256 + chunk*64 + k6)*9 + kk]
// deform: ti = g*9 + kk,     value = wd[(co*256 + g*64 + k6)*9 + kk]
__global__ __launch_bounds__(256) void prep_weights(
    const float* __restrict__ w1, const float* __restrict__ w2,
    const float* __restrict__ wd,
    ushort* __restrict__ wt1t, ushort* __restrict__ wt2t,
    ushort* __restrict__ wtdt) {
  const int N1 = 36 * 256 * 64;   // 589824
  const int N2 = 36 * 80 * 64;    // 184320
  const int N3 = 36 * 256 * 64;   // 589824
  int total = N1 + N2 + N3;
  for (int i = blockIdx.x * 256 + threadIdx.x; i < total; i += gridDim.x * 256) {
    if (i < N1) {
      int k6 = i & 63, co = (i >> 6) & 255, ti = i >> 14;
      int kk = ti >> 2, chunk = ti & 3;
      wt1t[i] = f2bf(w1[(co * 256 + chunk * 64 + k6) * 9 + kk]);
    } else if (i < N1 + N2) {
      int d = i - N1;
      int k6 = d & 63, r = d >> 6;
      int co = r % 80, ti = r / 80;
      int kk = ti >> 2, chunk = ti & 3;
      wt2t[d] = (co < 72) ? f2bf(w2[(co * 256 + chunk * 64 + k6) * 9 + kk])
                          : (ushort)0;
    } else {
      int d = i - N1 - N2;
      int k6 = d & 63, co = (d >> 6) & 255, ti = d >> 14;
      int g = ti / 9, kk = ti - g * 9;
      wtdt[d] = f2bf(wd[(co * 256 + g * 64 + k6) * 9 + kk]);
    }
  }
}

// ---------------- x -> channel-last grouped bf16 (verified R3-R5) ----------------
__global__ __launch_bounds__(256) void transpose_x(
    const float* __restrict__ x, ushort* __restrict__ xt) {
  int id = blockIdx.x;
  int y = id & 63, bg = id >> 6;
  int c = threadIdx.x & 63, xi = threadIdx.x >> 6;
  const float* ip = x + (((size_t)bg) << 18) + ((size_t)c << 12) + y * 64;
  ushort* op = xt + (((size_t)bg) << 18) + (size_t)y * 4096 + c;
#pragma unroll
  for (int j = 0; j < 16; ++j) {
    int xx = xi * 16 + j;
    op[(size_t)xx * 64] = f2bf(ip[xx]);
  }
}

// ---------------- unified MFMA kernel v5: barrier-free ----------------
// Block = (b,h) row [XCD swizzled], 2 independent waves; wave w owns px
// [w*32, w*32+32) (MFR=2), all CO_TILE=NFR*16 outputs. B fragments streamed
// from global (L2-broadcast, tile-major [ti][co][64]). No LDS, no barriers.
template <int MODE, int NFR, bool RELU, bool HASBIAS, bool OUT_CHLAST>
__global__ __launch_bounds__(128, 1) void fa_mfma5(
    const ushort* __restrict__ inT,  // [bg][4096 px][64 c] bf16
    const float* __restrict__ off,   // [B][72][64][64] f32 (MODE 1)
    const ushort* __restrict__ wB,   // [36][CO_TILE][64] bf16 tile-major
    const float* __restrict__ bias,
    void* __restrict__ outp,
    int co_total, int co_write) {
  constexpr int MFR = 2;
  constexpr int CO_TILE = NFR * 16;
  constexpr int NRN = (MODE == 1) ? 8 : 2;

  int id = blockIdx.x;
  int id2 = (id & 7) * 64 + (id >> 3);           // XCD swizzle (512 = 8*64)
  int b = id2 >> 6, h = id2 & 63;
  int t = threadIdx.x;
  int wv = t >> 6, lane = t & 63;
  int ml = lane & 15, kc = lane >> 4;

  int pcol[MFR];
#pragma unroll
  for (int mf = 0; mf < MFR; ++mf) pcol[mf] = wv * (MFR * 16) + mf * 16 + ml;

  const bf16x8 bz = {0, 0, 0, 0, 0, 0, 0, 0};
  bf16x8 aCur[MFR][2];
  bf16x8 rN[MFR][NRN];
  float wsv[MFR][4];
  float2 offA[MFR];

  // per-lane B base: fragment (nf, ks) of tile ti lives at
  // wB[((ti*CO_TILE + nf*16 + ml) << 6) + ks*32 + kc*8]
  const ushort* wBl = wB + (ml << 6) + kc * 8;

  // ---- MODE 0: direct conv A-path ----
  auto issueA0 = [&](int tn) {
    int kk = tn >> 2, chunk = tn & 3;
    int ky = kk / 3, kx = kk - ky * 3;
    int gy = h + ky - 1;
    bool rowok = (gy >= 0) & (gy < 64);
#pragma unroll
    for (int mf = 0; mf < MFR; ++mf) {
      int gx = pcol[mf] + kx - 1;
      bool inb = rowok & (gx >= 0) & (gx < 64);
      const ushort* p =
          inT + ((((size_t)(b * 4 + chunk) << 12) + gy * 64 + gx) << 6) + kc * 8;
      rN[mf][0] = bz;
      rN[mf][1] = bz;
      if (inb) {
        rN[mf][0] = *(const bf16x8*)p;
        rN[mf][1] = *(const bf16x8*)(p + 32);
      }
    }
  };
  auto finishA0 = [&]() {
#pragma unroll
    for (int mf = 0; mf < MFR; ++mf) {
      aCur[mf][0] = rN[mf][0];
      aCur[mf][1] = rN[mf][1];
    }
  };

  // ---- MODE 1: deform A-path ----
  auto loadOff = [&](int tn) {
    int g = tn / 9, kk = tn - 9 * (tn / 9);
    int ch = g * 18 + kk * 2;
#pragma unroll
    for (int mf = 0; mf < MFR; ++mf) {
      const float* offp =
          off + (((size_t)b * 72 + ch) << 12) + h * 64 + pcol[mf];
      offA[mf].x = offp[0];
      offA[mf].y = offp[4096];
    }
  };
  auto issueA1 = [&](int tn) {
    int g = tn / 9, kk = tn - 9 * (tn / 9);
    int ky = kk / 3, kx = kk - ky * 3;
    const ushort* base = inT + (((size_t)(b * 4 + g)) << 18) + kc * 8;
#pragma unroll
    for (int mf = 0; mf < MFR; ++mf) {
      float py = (float)(h + ky - 1) + offA[mf].x;
      float pxf = (float)(pcol[mf] + kx - 1) + offA[mf].y;
      float y0f = floorf(py), x0f = floorf(pxf);
      float wy1 = py - y0f, wx1 = pxf - x0f;
      float wy0 = 1.f - wy1, wx0 = 1.f - wx1;
      int y0 = (int)y0f, x0i = (int)x0f;
      int y1 = y0 + 1, x1i = x0i + 1;
      bool vy0 = (y0 >= 0) & (y0 < 64);
      bool vy1 = (y1 >= 0) & (y1 < 64);
      bool vx0 = (x0i >= 0) & (x0i < 64);
      bool vx1 = (x1i >= 0) & (x1i < 64);
      wsv[mf][0] = (vy0 & vx0) ? wy0 * wx0 : 0.f;
      wsv[mf][1] = (vy0 & vx1) ? wy0 * wx1 : 0.f;
      wsv[mf][2] = (vy1 & vx0) ? wy1 * wx0 : 0.f;
      wsv[mf][3] = (vy1 & vx1) ? wy1 * wx1 : 0.f;
      int yc0 = min(max(y0, 0), 63), yc1 = min(max(y1, 0), 63);
      int xc0 = min(max(x0i, 0), 63), xc1 = min(max(x1i, 0), 63);
      const ushort* p00 = base + ((yc0 * 64 + xc0) << 6);
      const ushort* p01 = base + ((yc0 * 64 + xc1) << 6);
      const ushort* p10 = base + ((yc1 * 64 + xc0) << 6);
      const ushort* p11 = base + ((yc1 * 64 + xc1) << 6);
      rN[mf][0] = *(const bf16x8*)p00;
      rN[mf][1] = *(const bf16x8*)(p00 + 32);
      rN[mf][2] = *(const bf16x8*)p01;
      rN[mf][3] = *(const bf16x8*)(p01 + 32);
      rN[mf][4] = *(const bf16x8*)p10;
      rN[mf][5] = *(const bf16x8*)(p10 + 32);
      rN[mf][6] = *(const bf16x8*)p11;
      rN[mf][7] = *(const bf16x8*)(p11 + 32);
    }
  };
  auto finishA1 = [&]() {
#pragma unroll
    for (int mf = 0; mf < MFR; ++mf) {
      float w00 = wsv[mf][0], w01 = wsv[mf][1];
      float w10 = wsv[mf][2], w11 = wsv[mf][3];
#pragma unroll
      for (int ks = 0; ks < 2; ++ks) {
        bf16x8 q00 = rN[mf][0 + ks], q01 = rN[mf][2 + ks];
        bf16x8 q10 = rN[mf][4 + ks], q11 = rN[mf][6 + ks];
        bf16x8 av;
#pragma unroll
        for (int jj = 0; jj < 4; ++jj) {
          float v0 = w00 * bf2f((ushort)q00[2 * jj]) + w01 * bf2f((ushort)q01[2 * jj]) +
                     w10 * bf2f((ushort)q10[2 * jj]) + w11 * bf2f((ushort)q11[2 * jj]);
          float v1 = w00 * bf2f((ushort)q00[2 * jj + 1]) + w01 * bf2f((ushort)q01[2 * jj + 1]) +
                     w10 * bf2f((ushort)q10[2 * jj + 1]) + w11 * bf2f((ushort)q11[2 * jj + 1]);
          av[2 * jj] = (short)f2bf(v0);
          av[2 * jj + 1] = (short)f2bf(v1);
        }
        aCur[mf][ks] = av;
      }
    }
  };

  f32x4 acc[MFR][NFR];
#pragma unroll
  for (int i = 0; i < MFR; ++i)
#pragma unroll
    for (int j = 0; j < NFR; ++j) acc[i][j] = (f32x4){0.f, 0.f, 0.f, 0.f};

  // prologue: build A(0); offsets for (1) prefetched
  if (MODE == 1) {
    loadOff(0);
    issueA1(0);
    loadOff(1);
    finishA1();
  } else {
    issueA0(0);
    finishA0();
  }

  for (int ti = 0; ti < 36; ++ti) {
    // issue next iteration's A gathers early (fly under this iter's MFMAs)
    if (ti < 35) {
      if (MODE == 1) issueA1(ti + 1); else issueA0(ti + 1);
    }
    if (MODE == 1 && ti < 34) loadOff(ti + 2);

    const ushort* wt = wBl + ((size_t)ti * CO_TILE << 6);

    // ks = 0 half: load 16 B-frags, MFMA
    {
      bf16x8 bq[NFR];
#pragma unroll
      for (int nf = 0; nf < NFR; ++nf)
        bq[nf] = *(const bf16x8*)(wt + (nf << 10));
#pragma unroll
      for (int mf = 0; mf < MFR; ++mf)
#pragma unroll
        for (int nf = 0; nf < NFR; ++nf)
          acc[mf][nf] = __builtin_amdgcn_mfma_f32_16x16x32_bf16(
              aCur[mf][0], bq[nf], acc[mf][nf], 0, 0, 0);
    }
    // ks = 1 half
    {
      bf16x8 bq[NFR];
#pragma unroll
      for (int nf = 0; nf < NFR; ++nf)
        bq[nf] = *(const bf16x8*)(wt + (nf << 10) + 32);
#pragma unroll
      for (int mf = 0; mf < MFR; ++mf)
#pragma unroll
        for (int nf = 0; nf < NFR; ++nf)
          acc[mf][nf] = __builtin_amdgcn_mfma_f32_16x16x32_bf16(
              aCur[mf][1], bq[nf], acc[mf][nf], 0, 0, 0);
    }

    if (ti < 35) { if (MODE == 1) finishA1(); else finishA0(); }
  }

  // epilogue: D col = lane&15 (co), row = (lane>>4)*4 + ri (px)
  int rq = lane >> 4;
#pragma unroll
  for (int nf = 0; nf < NFR; ++nf) {
    int cog = nf * 16 + ml;
    if (cog < co_write) {
      float bv = HASBIAS ? bias[cog] : 0.f;
#pragma unroll
      for (int mf = 0; mf < MFR; ++mf) {
#pragma unroll
        for (int ri = 0; ri < 4; ++ri) {
          int pxe = wv * (MFR * 16) + mf * 16 + rq * 4 + ri;
          float v = acc[mf][nf][ri] + bv;
          if (RELU) v = fmaxf(v, 0.f);
          if (OUT_CHLAST) {
            int g_out = cog >> 6, ci = cog & 63;
            ((ushort*)outp)[((((size_t)(b * 4 + g_out) << 12) + h * 64 + pxe) << 6) + ci] =
                f2bf(v);
          } else {
            ((float*)outp)[(((size_t)b * co_total + cog) << 12) + h * 64 + pxe] = v;
          }
        }
      }
    }
  }
}

extern "C" void kernel_launch(void* const* d_in, const int* in_sizes, int n_in,
                              void* d_out, int out_size, void* d_ws, size_t ws_size,
                              hipStream_t stream) {
  const float* x  = (const float*)d_in[0];
  const float* w1 = (const float*)d_in[1];
  const float* b1 = (const float*)d_in[2];
  const float* w2 = (const float*)d_in[3];
  const float* b2 = (const float*)d_in[4];
  const float* wd = (const float*)d_in[5];

  char* wsb = (char*)d_ws;
  float*  off_buf = (float*)wsb;                  //  9,437,184 B
  ushort* xt      = (ushort*)(wsb + 9437184);     // 16,777,216 B
  ushort* wt1t    = (ushort*)(wsb + 26214400);    //  1,179,648 B (36*256*64)
  ushort* wt2t    = (ushort*)(wsb + 27394048);    //    368,640 B (36*80*64)
  ushort* wtdt    = (ushort*)(wsb + 27762688);    //  1,179,648 B -> 28.9 MB

  prep_weights<<<2048, 256, 0, stream>>>(w1, w2, wd, wt1t, wt2t, wtdt);
  transpose_x<<<2048, 256, 0, stream>>>(x, xt);

  // conv1: xt -> t1t (bf16 channel-last in d_out); CO_TILE=256
  fa_mfma5<0, 16, false, true, true>
      <<<512, 128, 0, stream>>>(xt, nullptr, wt1t, b1, d_out, 256, 256);

  // conv2: t1t -> offsets (f32); CO_TILE=80
  fa_mfma5<0, 5, false, true, false>
      <<<512, 128, 0, stream>>>((const ushort*)d_out, nullptr, wt2t, b2,
                                off_buf, 72, 72);

  // deform + relu: xt, offsets -> d_out (f32)
  fa_mfma5<1, 16, true, false, false>
      <<<512, 128, 0, stream>>>(xt, off_buf, wtdt, nullptr, d_out, 256, 256);
}

// Round 7
// 189.088 us; speedup vs baseline: 2.2043x; 2.2043x over previous
//
#include <hip/hip_runtime.h>
#include <hip/hip_bf16.h>

// FeatureAdaption R7: R5 staged+swizzled structure, but MFR=1 wave tiles
// (16px x 256co) -> 2048 waves = 2 waves/SIMD, 4-wave blocks, no A-duplication.
// conv1(256->256) -> conv2(256->72)=offsets -> deform conv v1 + ReLU.
// B=8, C=256, H=W=64, dg=4, K=9.

typedef __attribute__((ext_vector_type(8))) short bf16x8;
typedef __attribute__((ext_vector_type(4))) float f32x4;

static __device__ __forceinline__ ushort f2bf(float f) {
  __hip_bfloat16 h = __float2bfloat16(f);
  return *reinterpret_cast<ushort*>(&h);
}
static __device__ __forceinline__ float bf2f(ushort u) {
  union { uint u32; float f; } cv;
  cv.u32 = ((uint)u) << 16;
  return cv.f;
}

// ---------------- weight prep: swizzled tiles (verified R5) ----------------
// Layout: [ti][co][p][e]; stored = orig[co][ ti*64 + (p ^ (co&7))*8 + e ]
__global__ __launch_bounds__(256) void prep_weights(
    const float* __restrict__ w1, const float* __restrict__ w2,
    const float* __restrict__ wd,
    ushort* __restrict__ wt1s, ushort* __restrict__ wt2s,
    ushort* __restrict__ wtds) {
  const int N1 = 36 * 256 * 64;
  const int N2 = 36 * 80 * 64;
  const int N3 = 36 * 256 * 64;
  int total = N1 + N2 + N3;
  for (int i = blockIdx.x * 256 + threadIdx.x; i < total; i += gridDim.x * 256) {
    if (i < N1) {
      int e = i & 7, p = (i >> 3) & 7, co = (i >> 6) & 255, ti = i >> 14;
      int cc = ((p ^ (co & 7)) << 3) + e;
      int kk = ti >> 2, chunk = ti & 3;
      wt1s[i] = f2bf(w1[(co * 256 + chunk * 64 + cc) * 9 + kk]);
    } else if (i < N1 + N2) {
      int d = i - N1;
      int e = d & 7, p = (d >> 3) & 7;
      int r = d >> 6;
      int co = r % 80, ti = r / 80;
      int cc = ((p ^ (co & 7)) << 3) + e;
      int kk = ti >> 2, chunk = ti & 3;
      wt2s[d] = (co < 72) ? f2bf(w2[(co * 256 + chunk * 64 + cc) * 9 + kk])
                          : (ushort)0;
    } else {
      int d = i - N1 - N2;
      int e = d & 7, p = (d >> 3) & 7, co = (d >> 6) & 255, ti = d >> 14;
      int c = ((p ^ (co & 7)) << 3) + e;
      int g = ti / 9, kk = ti - g * 9;
      wtds[d] = f2bf(wd[(co * 256 + g * 64 + c) * 9 + kk]);
    }
  }
}

// ---------------- x -> channel-last grouped bf16 (verified R3-R6) ----------------
__global__ __launch_bounds__(256) void transpose_x(
    const float* __restrict__ x, ushort* __restrict__ xt) {
  int id = blockIdx.x;
  int y = id & 63, bg = id >> 6;
  int c = threadIdx.x & 63, xi = threadIdx.x >> 6;
  const float* ip = x + (((size_t)bg) << 18) + ((size_t)c << 12) + y * 64;
  ushort* op = xt + (((size_t)bg) << 18) + (size_t)y * 4096 + c;
#pragma unroll
  for (int j = 0; j < 16; ++j) {
    int xx = xi * 16 + j;
    op[(size_t)xx * 64] = f2bf(ip[xx]);
  }
}

// ---------------- unified MFMA kernel v6: MFR=1, 4-wave blocks ----------------
// Block = (b,h) row [XCD swizzled], 4 waves; wave w owns px [w*16, w*16+16),
// all CO_TILE=NFR*16 outputs. B tile XOR-swizzled in LDS (conflict-free b128),
// double-buffered, staged linearly via global_load_lds from pre-swizzled src.
// A-path software-pipelined one iteration ahead (offsets two ahead).
template <int MODE, int NFR, bool RELU, bool HASBIAS, bool OUT_CHLAST>
__global__ __launch_bounds__(256, 2) void fa_mfma6(
    const ushort* __restrict__ inT,  // [bg][4096 px][64 c] bf16
    const float* __restrict__ off,   // [B][72][64][64] f32 (MODE 1)
    const char* __restrict__ wBs,    // swizzled tiles [36][CO_TILE*128 bytes]
    const float* __restrict__ bias,
    void* __restrict__ outp,
    int co_total, int co_write) {
  constexpr int CO_TILE = NFR * 16;
  constexpr int TILE_B = CO_TILE * 128;            // bytes per K-tile
  constexpr int NCALLS = (TILE_B + 4095) / 4096;   // 16B x 256thr per call
  constexpr int NRN = (MODE == 1) ? 8 : 2;
  __shared__ __align__(16) ushort Blds[2][NCALLS * 2048];

  int id = blockIdx.x;
  int id2 = (id & 7) * 64 + (id >> 3);             // XCD swizzle (512 = 8*64)
  int b = id2 >> 6, h = id2 & 63;
  int t = threadIdx.x;
  int wv = t >> 6, lane = t & 63;
  int ml = lane & 15, kc = lane >> 4;
  int ml7 = ml & 7;

  auto stage = [&](int ti, int bufsel) {
#pragma unroll
    for (int m = 0; m < NCALLS; ++m) {
      int d = (m * 256 + t) * 16;
      int ds = (d > TILE_B - 16) ? (TILE_B - 16) : d;   // clamp src (tail call)
      const char* src = wBs + (size_t)ti * TILE_B + ds;
      ushort* dst = &Blds[bufsel][(m * 256 + t) * 8];
      __builtin_amdgcn_global_load_lds(
          (const __attribute__((address_space(1))) void*)src,
          (__attribute__((address_space(3))) void*)dst, 16, 0, 0);
    }
  };

  const int pcol = wv * 16 + ml;                   // this lane's pixel column

  const bf16x8 bz = {0, 0, 0, 0, 0, 0, 0, 0};
  bf16x8 aCur[2];
  bf16x8 rN[NRN];
  float wsv[4];
  float2 offA;

  // ---- MODE 0: direct conv A-path ----
  auto issueA0 = [&](int tn) {
    int kk = tn >> 2, chunk = tn & 3;
    int ky = kk / 3, kx = kk - ky * 3;
    int gy = h + ky - 1, gx = pcol + kx - 1;
    bool inb = (gy >= 0) & (gy < 64) & (gx >= 0) & (gx < 64);
    const ushort* p =
        inT + ((((size_t)(b * 4 + chunk) << 12) + gy * 64 + gx) << 6) + kc * 8;
    rN[0] = bz;
    rN[1] = bz;
    if (inb) {
      rN[0] = *(const bf16x8*)p;
      rN[1] = *(const bf16x8*)(p + 32);
    }
  };
  auto finishA0 = [&]() {
    aCur[0] = rN[0];
    aCur[1] = rN[1];
  };

  // ---- MODE 1: deform A-path ----
  auto loadOff = [&](int tn) {
    int g = tn / 9, kk = tn - 9 * (tn / 9);
    int ch = g * 18 + kk * 2;
    const float* offp = off + (((size_t)b * 72 + ch) << 12) + h * 64 + pcol;
    offA.x = offp[0];
    offA.y = offp[4096];
  };
  auto issueA1 = [&](int tn) {
    int g = tn / 9, kk = tn - 9 * (tn / 9);
    int ky = kk / 3, kx = kk - ky * 3;
    const ushort* base = inT + (((size_t)(b * 4 + g)) << 18) + kc * 8;
    float py = (float)(h + ky - 1) + offA.x;
    float pxf = (float)(pcol + kx - 1) + offA.y;
    float y0f = floorf(py), x0f = floorf(pxf);
    float wy1 = py - y0f, wx1 = pxf - x0f;
    float wy0 = 1.f - wy1, wx0 = 1.f - wx1;
    int y0 = (int)y0f, x0i = (int)x0f;
    int y1 = y0 + 1, x1i = x0i + 1;
    bool vy0 = (y0 >= 0) & (y0 < 64);
    bool vy1 = (y1 >= 0) & (y1 < 64);
    bool vx0 = (x0i >= 0) & (x0i < 64);
    bool vx1 = (x1i >= 0) & (x1i < 64);
    wsv[0] = (vy0 & vx0) ? wy0 * wx0 : 0.f;
    wsv[1] = (vy0 & vx1) ? wy0 * wx1 : 0.f;
    wsv[2] = (vy1 & vx0) ? wy1 * wx0 : 0.f;
    wsv[3] = (vy1 & vx1) ? wy1 * wx1 : 0.f;
    int yc0 = min(max(y0, 0), 63), yc1 = min(max(y1, 0), 63);
    int xc0 = min(max(x0i, 0), 63), xc1 = min(max(x1i, 0), 63);
    const ushort* p00 = base + ((yc0 * 64 + xc0) << 6);
    const ushort* p01 = base + ((yc0 * 64 + xc1) << 6);
    const ushort* p10 = base + ((yc1 * 64 + xc0) << 6);
    const ushort* p11 = base + ((yc1 * 64 + xc1) << 6);
    rN[0] = *(const bf16x8*)p00;
    rN[1] = *(const bf16x8*)(p00 + 32);
    rN[2] = *(const bf16x8*)p01;
    rN[3] = *(const bf16x8*)(p01 + 32);
    rN[4] = *(const bf16x8*)p10;
    rN[5] = *(const bf16x8*)(p10 + 32);
    rN[6] = *(const bf16x8*)p11;
    rN[7] = *(const bf16x8*)(p11 + 32);
  };
  auto finishA1 = [&]() {
    float w00 = wsv[0], w01 = wsv[1], w10 = wsv[2], w11 = wsv[3];
#pragma unroll
    for (int ks = 0; ks < 2; ++ks) {
      bf16x8 q00 = rN[0 + ks], q01 = rN[2 + ks];
      bf16x8 q10 = rN[4 + ks], q11 = rN[6 + ks];
      bf16x8 av;
#pragma unroll
      for (int jj = 0; jj < 4; ++jj) {
        float v0 = w00 * bf2f((ushort)q00[2 * jj]) + w01 * bf2f((ushort)q01[2 * jj]) +
                   w10 * bf2f((ushort)q10[2 * jj]) + w11 * bf2f((ushort)q11[2 * jj]);
        float v1 = w00 * bf2f((ushort)q00[2 * jj + 1]) + w01 * bf2f((ushort)q01[2 * jj + 1]) +
                   w10 * bf2f((ushort)q10[2 * jj + 1]) + w11 * bf2f((ushort)q11[2 * jj + 1]);
        av[2 * jj] = (short)f2bf(v0);
        av[2 * jj + 1] = (short)f2bf(v1);
      }
      aCur[ks] = av;
    }
  };

  f32x4 acc[NFR];
#pragma unroll
  for (int j = 0; j < NFR; ++j) acc[j] = (f32x4){0.f, 0.f, 0.f, 0.f};

  // prologue
  if (MODE == 1) {
    loadOff(0);
    issueA1(0);
    loadOff(1);
    finishA1();
  } else {
    issueA0(0);
    finishA0();
  }
  stage(0, 0);
  __syncthreads();

  for (int ti = 0; ti < 36; ++ti) {
    int cur = ti & 1;
    if (ti < 35) {
      stage(ti + 1, cur ^ 1);
      if (MODE == 1) issueA1(ti + 1); else issueA0(ti + 1);
    }
    if (MODE == 1 && ti < 34) loadOff(ti + 2);

#pragma unroll
    for (int ks = 0; ks < 2; ++ks) {
      int sw = (((ks * 4 + kc) ^ ml7) << 3);       // swizzled 16B slot
      bf16x8 bq[NFR];
#pragma unroll
      for (int nf = 0; nf < NFR; ++nf)
        bq[nf] = *(const bf16x8*)&Blds[cur][(nf * 16 + ml) * 64 + sw];
#pragma unroll
      for (int nf = 0; nf < NFR; ++nf)
        acc[nf] = __builtin_amdgcn_mfma_f32_16x16x32_bf16(
            aCur[ks], bq[nf], acc[nf], 0, 0, 0);
    }

    if (ti < 35) { if (MODE == 1) finishA1(); else finishA0(); }
    __syncthreads();
  }

  // epilogue: D col = lane&15 (co), row = (lane>>4)*4 + ri (px)
  int rq = lane >> 4;
#pragma unroll
  for (int nf = 0; nf < NFR; ++nf) {
    int cog = nf * 16 + ml;
    if (cog < co_write) {
      float bv = HASBIAS ? bias[cog] : 0.f;
#pragma unroll
      for (int ri = 0; ri < 4; ++ri) {
        int pxe = wv * 16 + rq * 4 + ri;
        float v = acc[nf][ri] + bv;
        if (RELU) v = fmaxf(v, 0.f);
        if (OUT_CHLAST) {
          int g_out = cog >> 6, ci = cog & 63;
          ((ushort*)outp)[((((size_t)(b * 4 + g_out) << 12) + h * 64 + pxe) << 6) + ci] =
              f2bf(v);
        } else {
          ((float*)outp)[(((size_t)b * co_total + cog) << 12) + h * 64 + pxe] = v;
        }
      }
    }
  }
}

extern "C" void kernel_launch(void* const* d_in, const int* in_sizes, int n_in,
                              void* d_out, int out_size, void* d_ws, size_t ws_size,
                              hipStream_t stream) {
  const float* x  = (const float*)d_in[0];
  const float* w1 = (const float*)d_in[1];
  const float* b1 = (const float*)d_in[2];
  const float* w2 = (const float*)d_in[3];
  const float* b2 = (const float*)d_in[4];
  const float* wd = (const float*)d_in[5];

  char* wsb = (char*)d_ws;
  float*  off_buf = (float*)wsb;                  //  9,437,184 B
  ushort* xt      = (ushort*)(wsb + 9437184);     // 16,777,216 B
  ushort* wt1s    = (ushort*)(wsb + 26214400);    //  1,179,648 B (36*256*64)
  ushort* wt2s    = (ushort*)(wsb + 27394048);    //    368,640 B (36*80*64)
  ushort* wtds    = (ushort*)(wsb + 27762688);    //  1,179,648 B -> 28.9 MB

  prep_weights<<<2048, 256, 0, stream>>>(w1, w2, wd, wt1s, wt2s, wtds);
  transpose_x<<<2048, 256, 0, stream>>>(x, xt);

  // conv1: xt -> t1t (bf16 channel-last in d_out); CO_TILE=256, LDS 2x32KB
  fa_mfma6<0, 16, false, true, true>
      <<<512, 256, 0, stream>>>(xt, nullptr, (const char*)wt1s, b1, d_out, 256, 256);

  // conv2: t1t -> offsets (f32); CO_TILE=80, LDS 2x12KB
  fa_mfma6<0, 5, false, true, false>
      <<<512, 256, 0, stream>>>((const ushort*)d_out, nullptr, (const char*)wt2s,
                                b2, off_buf, 72, 72);

  // deform + relu: xt, offsets -> d_out (f32)
  fa_mfma6<1, 16, true, false, false>
      <<<512, 256, 0, stream>>>(xt, off_buf, (const char*)wtds, nullptr, d_out,
                                256, 256);
}